// Round 9
// baseline (949.066 us; speedup 1.0000x reference)
//
#include <hip/hip_runtime.h>

#define HH 512
#define WW 512
#define NC 25              // final channel count: 1 + 12*2
#define HWs (HH * WW)

__device__ __forceinline__ int refl(int p, int n) {
    p = (p < 0) ? -p : p;
    p = (p >= n) ? (2 * n - 2 - p) : p;
    return p;
}

__global__ __launch_bounds__(256) void copy_x_kernel(const float* __restrict__ x,
                                                     float* __restrict__ out) {
    int t = blockIdx.x * 256 + threadIdx.x;   // NB*HWs/4 = 262144 threads
    int b = t >> 16;                          // HWs/4 = 65536 float4 per batch
    int r = t & 65535;
    const float4* src = (const float4*)(x + (size_t)b * HWs);
    float4* dst = (float4*)(out + (size_t)b * NC * HWs);
    dst[r] = src[r];
}

// R8 kernel, unchanged (331.9 us measured): 6-row dilation-symmetry scheme,
// 24 dword loads / 6 px / channel, XCD swizzle, per-block channel rotation,
// ping-pong A/B buffers, (256,3) = 85-VGPR cap, ~2.7 blocks/CU.
template <int NIN, int DIL>
__global__ __launch_bounds__(256, 3) void msd_layer(const float* __restrict__ wts,
                                                    const float* __restrict__ bias,
                                                    float* __restrict__ buf,
                                                    int layer) {
    constexpr int M6 = 512 / (6 * DIL);
    constexpr int DM = DIL * M6;          // row-bases per image
    constexpr int SPAN = 6 * DM;          // rows covered by main path
    constexpr int RT = 512 - SPAN;        // tail rows (0..50)
    constexpr int TCH = (RT + 3) / 4;     // tail chunks of 4 rows
    constexpr int IMT = 512 * DM;         // main threads per image
    constexpr int NMAIN = 4 * IMT;

    int bid = blockIdx.x;
    {
        const int nblk = gridDim.x;
        const int q = nblk >> 3, r = nblk & 7;
        const int xcd = bid & 7, idx = bid >> 3;
        bid = (xcd < r ? xcd * (q + 1) : r * (q + 1) + (xcd - r) * q) + idx;
    }
    const int t = bid * 256 + threadIdx.x;

    const float b0 = bias[2 * layer];
    const float b1 = bias[2 * layer + 1];

    if (t < NMAIN) {
        const int img = t / IMT;                       // uniform per block
        const int u = t - img * IMT;
        const int bi = __builtin_amdgcn_readfirstlane(u >> 9);   // base index
        const int w = u & 511;                         // per-lane column
        const int k = bi / DIL, j = bi - k * DIL;
        const int h = 6 * DIL * k + j;                 // base output row (scalar)

        int rowoff[8];
#pragma unroll
        for (int r = 0; r < 8; ++r) rowoff[r] = refl(h + (r - 1) * DIL, HH) * WW;
        int cw[3];
#pragma unroll
        for (int q = 0; q < 3; ++q) cw[q] = refl(w + (q - 1) * DIL, WW);

        float a0[6], a1[6];
#pragma unroll
        for (int al = 0; al < 6; ++al) { a0[al] = b0; a1[al] = b1; }
        const float* base = buf + (size_t)img * NC * HWs;

        const int c0 = bid - (bid / NIN) * NIN;        // bid % NIN

        float vA[8][3], vB[8][3];

        auto LD = [&](float (&v)[8][3], int c) {
            const float* plane = base + (size_t)c * HWs;
#pragma unroll
            for (int r = 0; r < 8; ++r) {
                const float* rowp = plane + rowoff[r];
#pragma unroll
                for (int q = 0; q < 3; ++q) v[r][q] = rowp[cw[q]];
            }
        };
        auto FM = [&](const float (&v)[8][3], int c) {
            float wk0[9], wk1[9];
#pragma unroll
            for (int kk = 0; kk < 9; ++kk) {
                wk0[kk] = wts[c * 9 + kk];             // uniform -> s_load
                wk1[kk] = wts[(NIN + c) * 9 + kk];
            }
#pragma unroll
            for (int al = 0; al < 6; ++al)
#pragma unroll
                for (int kr = 0; kr < 3; ++kr)
#pragma unroll
                    for (int kw = 0; kw < 3; ++kw) {
                        float vv = v[al + kr][kw];
                        a0[al] = fmaf(vv, wk0[kr * 3 + kw], a0[al]);
                        a1[al] = fmaf(vv, wk1[kr * 3 + kw], a1[al]);
                    }
        };

        LD(vA, c0);
#pragma unroll
        for (int i = 0; i < NIN; i += 2) {
            int cA = c0 + i;     cA -= (cA >= NIN) ? NIN : 0;
            int cB = c0 + i + 1; cB -= (cB >= NIN) ? NIN : 0;
            if (i + 1 < NIN) LD(vB, cB);
            FM(vA, cA);
            if (i + 1 >= NIN) break;
            int cN = c0 + i + 2; cN -= (cN >= NIN) ? NIN : 0;
            if (i + 2 < NIN) LD(vA, cN);
            FM(vB, cB);
        }

        float* o0 = buf + (size_t)(img * NC + NIN) * HWs;
        float* o1 = o0 + HWs;
#pragma unroll
        for (int al = 0; al < 6; ++al) {
            size_t off = (size_t)(h + al * DIL) * WW + (size_t)w;
            o0[off] = fmaxf(a0[al], 0.f);
            o1[off] = fmaxf(a1[al], 0.f);
        }
    } else if (RT > 0) {
        const int t2 = t - NMAIN;
        constexpr int PIT = 512 * TCH;
        const int img = t2 / PIT;
        const int u = t2 - img * PIT;
        const int s = __builtin_amdgcn_readfirstlane(u >> 9);
        const int w = u & 511;
        const int r0 = SPAN + 4 * s;

        int cw[3];
#pragma unroll
        for (int q = 0; q < 3; ++q) cw[q] = refl(w + (q - 1) * DIL, WW);
        int ro[3][4];
#pragma unroll
        for (int kr = 0; kr < 3; ++kr)
#pragma unroll
            for (int i = 0; i < 4; ++i)
                ro[kr][i] = refl(r0 + i + (kr - 1) * DIL, HH) * WW;

        float a0[4] = {b0, b0, b0, b0};
        float a1[4] = {b1, b1, b1, b1};
        const float* base = buf + (size_t)img * NC * HWs;

        for (int c = 0; c < NIN; ++c) {
            const float* plane = base + (size_t)c * HWs;
            float wk0[9], wk1[9];
#pragma unroll
            for (int kk = 0; kk < 9; ++kk) {
                wk0[kk] = wts[c * 9 + kk];
                wk1[kk] = wts[(NIN + c) * 9 + kk];
            }
#pragma unroll
            for (int i = 0; i < 4; ++i) {
                if (r0 + i < HH) {
#pragma unroll
                    for (int kr = 0; kr < 3; ++kr) {
                        const float* rowp = plane + ro[kr][i];
#pragma unroll
                        for (int kw = 0; kw < 3; ++kw) {
                            float vv = rowp[cw[kw]];
                            a0[i] = fmaf(vv, wk0[kr * 3 + kw], a0[i]);
                            a1[i] = fmaf(vv, wk1[kr * 3 + kw], a1[i]);
                        }
                    }
                }
            }
        }

        float* o0 = buf + (size_t)(img * NC + NIN) * HWs;
        float* o1 = o0 + HWs;
#pragma unroll
        for (int i = 0; i < 4; ++i) {
            if (r0 + i < HH) {
                size_t off = (size_t)(r0 + i) * WW + (size_t)w;
                o0[off] = fmaxf(a0[i], 0.f);
                o1[off] = fmaxf(a1[i], 0.f);
            }
        }
    }
}

// ======================= R9 DIAGNOSTICS (write-free) =======================
// Ablation per methodology: decompose the pipeline into load-side and
// FMA-side components, x3 repeats so each diagnostic exceeds the 63us
// top-5 threshold and surfaces full rocprof counters. Removed next round.

template <int NIN, int DIL>
__device__ __forceinline__ void diag_load_body(const float* __restrict__ buf, int t) {
    constexpr int M6 = 512 / (6 * DIL);
    constexpr int DM = DIL * M6;
    constexpr int IMT = 512 * DM;
    constexpr int NMAIN = 4 * IMT;
    if (t >= NMAIN) return;
    const int img = t / IMT;
    const int u = t - img * IMT;
    const int bi = __builtin_amdgcn_readfirstlane(u >> 9);
    const int w = u & 511;
    const int k = bi / DIL, j = bi - k * DIL;
    const int h = 6 * DIL * k + j;
    int rowoff[8];
#pragma unroll
    for (int r = 0; r < 8; ++r) rowoff[r] = refl(h + (r - 1) * DIL, HH) * WW;
    int cw[3];
#pragma unroll
    for (int q = 0; q < 3; ++q) cw[q] = refl(w + (q - 1) * DIL, WW);
    const float* base = buf + (size_t)img * NC * HWs;

    float vA[8][3], vB[8][3];
    auto LD = [&](float (&v)[8][3], int c) {
        const float* plane = base + (size_t)c * HWs;
#pragma unroll
        for (int r = 0; r < 8; ++r) {
            const float* rowp = plane + rowoff[r];
#pragma unroll
            for (int q = 0; q < 3; ++q) v[r][q] = rowp[cw[q]];
        }
    };
    auto SINK = [&](float (&v)[8][3]) {     // stands in for FM: forces the
#pragma unroll                               // waitcnt, costs zero VALU
        for (int r = 0; r < 8; ++r)
#pragma unroll
            for (int q = 0; q < 3; ++q) asm volatile("" :: "v"(v[r][q]));
    };

    LD(vA, 0);
#pragma unroll
    for (int i = 0; i < NIN; i += 2) {
        if (i + 1 < NIN) LD(vB, i + 1);
        SINK(vA);
        if (i + 1 >= NIN) break;
        if (i + 2 < NIN) LD(vA, i + 2);
        SINK(vB);
    }
}

template <int NIN, int DIL>
__device__ __forceinline__ void diag_fma_body(const float* __restrict__ buf,
                                              const float* __restrict__ wts, int t) {
    constexpr int M6 = 512 / (6 * DIL);
    constexpr int DM = DIL * M6;
    constexpr int IMT = 512 * DM;
    constexpr int NMAIN = 4 * IMT;
    if (t >= NMAIN) return;
    const int img = t / IMT;
    const int u = t - img * IMT;
    const int bi = __builtin_amdgcn_readfirstlane(u >> 9);
    const int w = u & 511;
    const int k = bi / DIL, j = bi - k * DIL;
    const int h = 6 * DIL * k + j;
    int rowoff[8];
#pragma unroll
    for (int r = 0; r < 8; ++r) rowoff[r] = refl(h + (r - 1) * DIL, HH) * WW;
    int cw[3];
#pragma unroll
    for (int q = 0; q < 3; ++q) cw[q] = refl(w + (q - 1) * DIL, WW);
    const float* base = buf + (size_t)img * NC * HWs;

    float a0[6] = {0, 0, 0, 0, 0, 0}, a1[6] = {0, 0, 0, 0, 0, 0};
    float vA[8][3];
    {   // load ONE channel block; reuse it for all NIN FMA sweeps
        const float* plane = base;
#pragma unroll
        for (int r = 0; r < 8; ++r) {
            const float* rowp = plane + rowoff[r];
#pragma unroll
            for (int q = 0; q < 3; ++q) vA[r][q] = rowp[cw[q]];
        }
    }
#pragma unroll
    for (int c = 0; c < NIN; ++c) {
        float wk0[9], wk1[9];
#pragma unroll
        for (int kk = 0; kk < 9; ++kk) {
            wk0[kk] = wts[c * 9 + kk];
            wk1[kk] = wts[(NIN + c) * 9 + kk];
        }
#pragma unroll
        for (int al = 0; al < 6; ++al)
#pragma unroll
            for (int kr = 0; kr < 3; ++kr)
#pragma unroll
                for (int kw = 0; kw < 3; ++kw) {
                    float vv = vA[al + kr][kw];
                    a0[al] = fmaf(vv, wk0[kr * 3 + kw], a0[al]);
                    a1[al] = fmaf(vv, wk1[kr * 3 + kw], a1[al]);
                }
    }
#pragma unroll
    for (int al = 0; al < 6; ++al) {
        asm volatile("" :: "v"(a0[al]));
        asm volatile("" :: "v"(a1[al]));
    }
}

struct WPtrs { const float* w[12]; };

__global__ __launch_bounds__(256, 3) void diag_loads_all(const float* __restrict__ buf,
                                                         int rep) {
    int bid = blockIdx.x;
    {
        const int nblk = gridDim.x;
        const int q = nblk >> 3, r = nblk & 7;
        const int xcd = bid & 7, idx = bid >> 3;
        bid = (xcd < r ? xcd * (q + 1) : r * (q + 1) + (xcd - r) * q) + idx;
    }
    const int t = bid * 256 + threadIdx.x;
#pragma unroll 1
    for (int s = 0; s < rep; ++s) {
        diag_load_body<1, 1>(buf, t);
        diag_load_body<3, 2>(buf, t);
        diag_load_body<5, 3>(buf, t);
        diag_load_body<7, 4>(buf, t);
        diag_load_body<9, 5>(buf, t);
        diag_load_body<11, 6>(buf, t);
        diag_load_body<13, 7>(buf, t);
        diag_load_body<15, 8>(buf, t);
        diag_load_body<17, 9>(buf, t);
        diag_load_body<19, 10>(buf, t);
        diag_load_body<21, 11>(buf, t);
        diag_load_body<23, 12>(buf, t);
        asm volatile("" ::: "memory");   // force reloads each sweep
    }
}

__global__ __launch_bounds__(256, 3) void diag_fma_all(const float* __restrict__ buf,
                                                       WPtrs wp, int rep) {
    int bid = blockIdx.x;
    {
        const int nblk = gridDim.x;
        const int q = nblk >> 3, r = nblk & 7;
        const int xcd = bid & 7, idx = bid >> 3;
        bid = (xcd < r ? xcd * (q + 1) : r * (q + 1) + (xcd - r) * q) + idx;
    }
    const int t = bid * 256 + threadIdx.x;
#pragma unroll 1
    for (int s = 0; s < rep; ++s) {
        diag_fma_body<1, 1>(buf, wp.w[0], t);
        diag_fma_body<3, 2>(buf, wp.w[1], t);
        diag_fma_body<5, 3>(buf, wp.w[2], t);
        diag_fma_body<7, 4>(buf, wp.w[3], t);
        diag_fma_body<9, 5>(buf, wp.w[4], t);
        diag_fma_body<11, 6>(buf, wp.w[5], t);
        diag_fma_body<13, 7>(buf, wp.w[6], t);
        diag_fma_body<15, 8>(buf, wp.w[7], t);
        diag_fma_body<17, 9>(buf, wp.w[8], t);
        diag_fma_body<19, 10>(buf, wp.w[9], t);
        diag_fma_body<21, 11>(buf, wp.w[10], t);
        diag_fma_body<23, 12>(buf, wp.w[11], t);
        asm volatile("" ::: "memory");
    }
}

extern "C" void kernel_launch(void* const* d_in, const int* in_sizes, int n_in,
                              void* d_out, int out_size, void* d_ws, size_t ws_size,
                              hipStream_t stream) {
    const float* x = (const float*)d_in[0];
    const float* bias = (const float*)d_in[1];
    float* out = (float*)d_out;

    copy_x_kernel<<<1024, 256, 0, stream>>>(x, out);

// blocks = (main + tail threads)/256 = 8*DM + 8*TCH  (6-row scheme)
#define GBLK(dil) (8 * ((dil) * (512 / (6 * (dil)))) \
                 + 8 * (((512 - 6 * ((dil) * (512 / (6 * (dil))))) + 3) / 4))
#define LAYER(i, nin, dil) \
    msd_layer<nin, dil><<<GBLK(dil), 256, 0, stream>>>((const float*)d_in[2 + i], bias, out, i)

    LAYER(0, 1, 1);
    LAYER(1, 3, 2);
    LAYER(2, 5, 3);
    LAYER(3, 7, 4);
    LAYER(4, 9, 5);
    LAYER(5, 11, 6);
    LAYER(6, 13, 7);
    LAYER(7, 15, 8);
    LAYER(8, 17, 9);
    LAYER(9, 19, 10);
    LAYER(10, 21, 11);
    LAYER(11, 23, 12);
#undef LAYER
#undef GBLK

    // -------- diagnostics (write-free; read the finished buffer) --------
    WPtrs wp;
    for (int i = 0; i < 12; ++i) wp.w[i] = (const float*)d_in[2 + i];
    diag_loads_all<<<680, 256, 0, stream>>>(out, 3);
    diag_fma_all<<<680, 256, 0, stream>>>(out, wp, 3);
}

// Round 10
// 494.070 us; speedup vs baseline: 1.9209x; 1.9209x over previous
//
#include <hip/hip_runtime.h>

#define HH 512
#define WW 512
#define NC 25              // final channel count: 1 + 12*2
#define HWs (HH * WW)

__device__ __forceinline__ int refl(int p, int n) {
    p = (p < 0) ? -p : p;
    p = (p >= n) ? (2 * n - 2 - p) : p;
    return p;
}

__global__ __launch_bounds__(256) void copy_x_kernel(const float* __restrict__ x,
                                                     float* __restrict__ out) {
    int t = blockIdx.x * 256 + threadIdx.x;   // NB*HWs/4 = 262144 threads
    int b = t >> 16;                          // HWs/4 = 65536 float4 per batch
    int r = t & 65535;
    const float4* src = (const float4*)(x + (size_t)b * HWs);
    float4* dst = (float4*)(out + (size_t)b * NC * HWs);
    dst[r] = src[r];
}

// R10: depth round. R9 ablation: load-side 130us (request-rate-bound,
// ~7.8cyc/wave-load), FMA-side 75us, pipeline ~= SUM not MAX -> ~100us of
// dependency stall (1-deep ping-pong covers only ~216 VALU cyc vs 300-900cyc
// L2miss/L3 latency). waves/SIMD x per-channel-cycles is invariant across
// K-row variants (both ∝ VGPR budget) — deeper prefetch is the only escape
// at fixed VGPR. 4-row scheme + THREE buffers, prefetch 2 channels ahead:
// issue->use distance ~2x288 VALU cyc, MLP 36 outstanding/wave.
// (256,2) = 128-VGPR cap: ~85-90 live fits, NO spill (R5 lesson: tighter
// caps spill catastrophically). Grid = exactly 1024 blocks for every DIL.
template <int NIN, int DIL>
__global__ __launch_bounds__(256, 2) void msd_layer(const float* __restrict__ wts,
                                                    const float* __restrict__ bias,
                                                    float* __restrict__ buf,
                                                    int layer) {
    constexpr int M4 = 512 / (4 * DIL);
    constexpr int DM = DIL * M4;          // row-bases per image
    constexpr int SPAN = 4 * DM;          // rows covered by main path
    constexpr int RT = 512 - SPAN;        // tail rows (0..32)
    constexpr int TCH = (RT + 3) / 4;     // tail chunks of 4 rows
    constexpr int IMT = 512 * DM;         // main threads per image
    constexpr int NMAIN = 4 * IMT;

    // ---- bijective chunked XCD swizzle (MI355X: 8 XCDs, round-robin) ----
    int bid = blockIdx.x;
    {
        const int nblk = gridDim.x;
        const int q = nblk >> 3, r = nblk & 7;
        const int xcd = bid & 7, idx = bid >> 3;
        bid = (xcd < r ? xcd * (q + 1) : r * (q + 1) + (xcd - r) * q) + idx;
    }
    const int t = bid * 256 + threadIdx.x;

    const float b0 = bias[2 * layer];
    const float b1 = bias[2 * layer + 1];

    if (t < NMAIN) {
        const int img = t / IMT;                       // uniform per block
        const int u = t - img * IMT;
        const int bi = __builtin_amdgcn_readfirstlane(u >> 9);   // base index
        const int w = u & 511;                         // per-lane column
        const int k = bi / DIL, j = bi - k * DIL;
        const int h = 4 * DIL * k + j;                 // base output row (scalar)

        int rowoff[6];                                 // rows h+(r-1)*d, scalar
#pragma unroll
        for (int r = 0; r < 6; ++r) rowoff[r] = refl(h + (r - 1) * DIL, HH) * WW;
        int cw[3];                                     // per-lane col taps
#pragma unroll
        for (int q = 0; q < 3; ++q) cw[q] = refl(w + (q - 1) * DIL, WW);

        float a0[4], a1[4];
#pragma unroll
        for (int al = 0; al < 4; ++al) { a0[al] = b0; a1[al] = b1; }
        const float* base = buf + (size_t)img * NC * HWs;

        // per-block channel-rotation start (scalar; NIN is compile-time)
        const int c0 = bid - (bid / NIN) * NIN;        // bid % NIN

        float v0[6][3], v1[6][3], v2[6][3];            // 3-deep rotation

        auto LD = [&](float (&v)[6][3], int c) {
            int cc = c0 + c; cc -= (cc >= NIN) ? NIN : 0;
            const float* plane = base + (size_t)cc * HWs;
#pragma unroll
            for (int r = 0; r < 6; ++r) {
                const float* rowp = plane + rowoff[r];
#pragma unroll
                for (int q = 0; q < 3; ++q) v[r][q] = rowp[cw[q]];
            }
        };
        auto FM = [&](const float (&v)[6][3], int c) {
            int cc = c0 + c; cc -= (cc >= NIN) ? NIN : 0;
            float wk0[9], wk1[9];
#pragma unroll
            for (int kk = 0; kk < 9; ++kk) {
                wk0[kk] = wts[cc * 9 + kk];            // uniform -> s_load
                wk1[kk] = wts[(NIN + cc) * 9 + kk];
            }
#pragma unroll
            for (int al = 0; al < 4; ++al)
#pragma unroll
                for (int kr = 0; kr < 3; ++kr)
#pragma unroll
                    for (int kw = 0; kw < 3; ++kw) {
                        float vv = v[al + kr][kw];
                        a0[al] = fmaf(vv, wk0[kr * 3 + kw], a0[al]);
                        a1[al] = fmaf(vv, wk1[kr * 3 + kw], a1[al]);
                    }
        };

        LD(v0, 0);
        if (1 < NIN) LD(v1, 1);
#pragma unroll
        for (int c = 0; c < NIN; ++c) {
            // static buffer selection (c is a compile-time unroll constant)
            float (&cur)[6][3] = (c % 3 == 0) ? v0 : ((c % 3 == 1) ? v1 : v2);
            float (&nxt)[6][3] = ((c + 2) % 3 == 0) ? v0
                               : (((c + 2) % 3 == 1) ? v1 : v2);
            if (c + 2 < NIN) LD(nxt, c + 2);           // 2-channel-deep prefetch
            FM(cur, c);
        }

        float* o0 = buf + (size_t)(img * NC + NIN) * HWs;
        float* o1 = o0 + HWs;
#pragma unroll
        for (int al = 0; al < 4; ++al) {
            size_t off = (size_t)(h + al * DIL) * WW + (size_t)w;
            o0[off] = fmaxf(a0[al], 0.f);
            o1[off] = fmaxf(a1[al], 0.f);
        }
    } else if (RT > 0) {
        const int t2 = t - NMAIN;
        constexpr int PIT = 512 * TCH;
        const int img = t2 / PIT;
        const int u = t2 - img * PIT;
        const int s = __builtin_amdgcn_readfirstlane(u >> 9);
        const int w = u & 511;
        const int r0 = SPAN + 4 * s;

        int cw[3];
#pragma unroll
        for (int q = 0; q < 3; ++q) cw[q] = refl(w + (q - 1) * DIL, WW);
        int ro[3][4];
#pragma unroll
        for (int kr = 0; kr < 3; ++kr)
#pragma unroll
            for (int i = 0; i < 4; ++i)
                ro[kr][i] = refl(r0 + i + (kr - 1) * DIL, HH) * WW;

        float a0[4] = {b0, b0, b0, b0};
        float a1[4] = {b1, b1, b1, b1};
        const float* base = buf + (size_t)img * NC * HWs;

        for (int c = 0; c < NIN; ++c) {
            const float* plane = base + (size_t)c * HWs;
            float wk0[9], wk1[9];
#pragma unroll
            for (int kk = 0; kk < 9; ++kk) {
                wk0[kk] = wts[c * 9 + kk];
                wk1[kk] = wts[(NIN + c) * 9 + kk];
            }
#pragma unroll
            for (int i = 0; i < 4; ++i) {
                if (r0 + i < HH) {
#pragma unroll
                    for (int kr = 0; kr < 3; ++kr) {
                        const float* rowp = plane + ro[kr][i];
#pragma unroll
                        for (int kw = 0; kw < 3; ++kw) {
                            float vv = rowp[cw[kw]];
                            a0[i] = fmaf(vv, wk0[kr * 3 + kw], a0[i]);
                            a1[i] = fmaf(vv, wk1[kr * 3 + kw], a1[i]);
                        }
                    }
                }
            }
        }

        float* o0 = buf + (size_t)(img * NC + NIN) * HWs;
        float* o1 = o0 + HWs;
#pragma unroll
        for (int i = 0; i < 4; ++i) {
            if (r0 + i < HH) {
                size_t off = (size_t)(r0 + i) * WW + (size_t)w;
                o0[off] = fmaxf(a0[i], 0.f);
                o1[off] = fmaxf(a1[i], 0.f);
            }
        }
    }
}

extern "C" void kernel_launch(void* const* d_in, const int* in_sizes, int n_in,
                              void* d_out, int out_size, void* d_ws, size_t ws_size,
                              hipStream_t stream) {
    const float* x = (const float*)d_in[0];
    const float* bias = (const float*)d_in[1];
    float* out = (float*)d_out;

    copy_x_kernel<<<1024, 256, 0, stream>>>(x, out);

// blocks = (main + tail threads)/256 = 8*DM + 8*TCH  (4-row scheme; = 1024
// exactly for every DIL in 1..12)
#define GBLK(dil) (8 * ((dil) * (512 / (4 * (dil)))) \
                 + 8 * (((512 - 4 * ((dil) * (512 / (4 * (dil))))) + 3) / 4))
#define LAYER(i, nin, dil) \
    msd_layer<nin, dil><<<GBLK(dil), 256, 0, stream>>>((const float*)d_in[2 + i], bias, out, i)

    LAYER(0, 1, 1);
    LAYER(1, 3, 2);
    LAYER(2, 5, 3);
    LAYER(3, 7, 4);
    LAYER(4, 9, 5);
    LAYER(5, 11, 6);
    LAYER(6, 13, 7);
    LAYER(7, 15, 8);
    LAYER(8, 17, 9);
    LAYER(9, 19, 10);
    LAYER(10, 21, 11);
    LAYER(11, 23, 12);
#undef LAYER
#undef GBLK
}